// Round 4
// baseline (474.500 us; speedup 1.0000x reference)
//
#include <hip/hip_runtime.h>

#define B_   64
#define C_   12
#define NC_  16
#define N0_  2048
#define N1_  1000
#define N2_  500
#define N3_  100
#define AGENT __HIP_MEMORY_SCOPE_AGENT

__device__ __forceinline__ float wred(float v) {
#pragma unroll
    for (int off = 32; off > 0; off >>= 1) v += __shfl_xor(v, off, 64);
    return v;
}

// ===== K1: h1 = relu(x·W1b^T + b1b). grid (125,12)×256, 2 rows/wave. =====
// Block (0,0) additionally zeroes the K2 counter/accumulator region.
__global__ __launch_bounds__(256)
void k_l1b(const float* __restrict__ x, const int* __restrict__ cls,
           const float* __restrict__ W1b, const float* __restrict__ b1b,
           float* __restrict__ h1, int* __restrict__ zbase) {
    if (blockIdx.x == 0 && blockIdx.y == 0) {
        for (int i = threadIdx.x; i < 1416; i += 256) zbase[i] = 0;   // 5664 B
    }
    const int c    = blockIdx.y;
    const int lane = threadIdx.x & 63;
    const int wave = threadIdx.x >> 6;
    const unsigned long long m = __ballot(cls[lane] == c);
    if (m == 0ull) return;

    const int j0 = blockIdx.x * 8 + wave * 2;                 // < 1000 always
    const float4* wr0 = (const float4*)(W1b + ((size_t)c * N1_ + j0) * N0_);
    const float4* wr1 = wr0 + (N0_ / 4);
    float4 w0[8], w1[8];
#pragma unroll
    for (int f = 0; f < 8; ++f) { w0[f] = wr0[f * 64 + lane]; w1[f] = wr1[f * 64 + lane]; }
    const float bias0 = b1b[c * N1_ + j0];
    const float bias1 = b1b[c * N1_ + j0 + 1];

    for (unsigned long long mm = m; mm; mm &= (mm - 1ull)) {
        const int b = (int)__builtin_ctzll(mm);
        const float4* xr = (const float4*)(x + (size_t)b * N0_);
        float a0 = 0.f, a1 = 0.f;
#pragma unroll
        for (int f = 0; f < 8; ++f) {
            const float4 xv = xr[f * 64 + lane];
            a0 += w0[f].x * xv.x + w0[f].y * xv.y + w0[f].z * xv.z + w0[f].w * xv.w;
            a1 += w1[f].x * xv.x + w1[f].y * xv.y + w1[f].z * xv.z + w1[f].w * xv.w;
        }
        const float s0 = wred(a0), s1 = wred(a1);
        if (lane == 0) {
            h1[(size_t)b * N1_ + j0]     = fmaxf(s0 + bias0, 0.f);
            h1[(size_t)b * N1_ + j0 + 1] = fmaxf(s1 + bias1, 0.f);
        }
    }
}

// ===== K2: fused l2b -> y1/argmax -> l1r -> y2 head. Work-stealing + atomics only. =====
__global__ __launch_bounds__(256)
void k_fused2(const float* __restrict__ x, const int* __restrict__ cls,
              const float* __restrict__ h1,
              const float* __restrict__ W2b, const float* __restrict__ b2b,
              const float* __restrict__ W3b, const float* __restrict__ b3b,
              const float* __restrict__ W1r, const float* __restrict__ b1r,
              const float* __restrict__ W2r, const float* __restrict__ b2r,
              float* __restrict__ y1acc, int* __restrict__ cntb,
              int* __restrict__ flag,  int* __restrict__ cntr,
              float* __restrict__ y2acc, int* __restrict__ ctrs,
              float* __restrict__ out_y1, float* __restrict__ out_y2) {
    const int lane = threadIdx.x & 63;
    const int cls_lane = cls[lane];
    const float4 z4 = make_float4(0.f, 0.f, 0.f, 0.f);

    // ---------- P2: l2b task (c, j0-pair); h2 pair stays in registers ----------
    for (;;) {
        int t = 0;
        if (lane == 0) t = __hip_atomic_fetch_add(&ctrs[0], 1, __ATOMIC_RELAXED, AGENT);
        t = __shfl(t, 0, 64);
        if (t >= C_ * (N2_ / 2)) break;                       // 3000 tasks
        const int c  = t / (N2_ / 2);
        const int j0 = (t % (N2_ / 2)) * 2;
        const unsigned long long m = __ballot(cls_lane == c);
        if (m == 0ull) continue;

        const float4* wr0 = (const float4*)(W2b + ((size_t)c * N2_ + j0) * N1_);
        const float4* wr1 = wr0 + (N1_ / 4);
        float4 w0[4], w1[4];
#pragma unroll
        for (int f = 0; f < 4; ++f) {
            const int idx = f * 64 + lane;
            const bool v = (idx < N1_ / 4);
            w0[f] = v ? wr0[idx] : z4;
            w1[f] = v ? wr1[idx] : z4;
        }
        const float bias0 = b2b[c * N2_ + j0];
        const float bias1 = b2b[c * N2_ + j0 + 1];
        float w3_0 = 0.f, w3_1 = 0.f;                         // lane m's W3 pair (task-invariant)
        if (lane < NC_) {
            const float* w3r = W3b + ((size_t)c * NC_ + lane) * N2_ + j0;
            w3_0 = w3r[0]; w3_1 = w3r[1];
        }

        for (unsigned long long mm = m; mm; mm &= (mm - 1ull)) {
            const int b = (int)__builtin_ctzll(mm);
            const float4* xr = (const float4*)(h1 + (size_t)b * N1_);
            float a0 = 0.f, a1 = 0.f;
#pragma unroll
            for (int f = 0; f < 4; ++f) {
                const int idx = f * 64 + lane;
                const float4 xv = (idx < N1_ / 4) ? xr[idx] : z4;
                a0 += w0[f].x * xv.x + w0[f].y * xv.y + w0[f].z * xv.z + w0[f].w * xv.w;
                a1 += w1[f].x * xv.x + w1[f].y * xv.y + w1[f].z * xv.z + w1[f].w * xv.w;
            }
            const float s0 = fmaxf(wred(a0) + bias0, 0.f);    // h2[b][j0]   (all lanes)
            const float s1 = fmaxf(wred(a1) + bias1, 0.f);    // h2[b][j0+1]
            if (lane < NC_)
                __hip_atomic_fetch_add(&y1acc[b * NC_ + lane], s0 * w3_0 + s1 * w3_1,
                                       __ATOMIC_RELAXED, AGENT);
            int old = 0;
            if (lane == 0) old = __hip_atomic_fetch_add(&cntb[b], 1, __ATOMIC_ACQ_REL, AGENT);
            old = __shfl(old, 0, 64);
            if (old == N2_ / 2 - 1) {                         // last l2b task for this b
                float v = -1e30f;
                if (lane < NC_) {
                    v = __hip_atomic_load(&y1acc[b * NC_ + lane], __ATOMIC_RELAXED, AGENT)
                        + b3b[c * NC_ + lane];
                    out_y1[b * NC_ + lane] = v;
                }
                int mi = lane;                                 // argmax, first occurrence
#pragma unroll
                for (int off = 8; off > 0; off >>= 1) {
                    const float ov = __shfl_xor(v,  off, 64);
                    const int   om = __shfl_xor(mi, off, 64);
                    if (ov > v || (ov == v && om < mi)) { v = ov; mi = om; }
                }
                if (lane == 0)
                    __hip_atomic_store(&flag[b], 1 + c * NC_ + mi, __ATOMIC_RELEASE, AGENT);
            }
        }
    }

    // ---------- P4: r-path task (b, j0-pair) + fused head ----------
    for (;;) {
        int t = 0;
        if (lane == 0) t = __hip_atomic_fetch_add(&ctrs[1], 1, __ATOMIC_RELAXED, AGENT);
        t = __shfl(t, 0, 64);
        if (t >= B_ * (N3_ / 2)) break;                       // 3200 tasks
        const int b  = t / (N3_ / 2);
        const int j0 = (t % (N3_ / 2)) * 2;

        int fv = 0;
        if (lane == 0) {
            while ((fv = __hip_atomic_load(&flag[b], __ATOMIC_RELAXED, AGENT)) == 0)
                __builtin_amdgcn_s_sleep(2);
        }
        fv = __shfl(fv, 0, 64);
        const int e = fv - 1;

        const float4* wr0 = (const float4*)(W1r + ((size_t)e * N3_ + j0) * N0_);
        const float4* wr1 = wr0 + (N0_ / 4);
        float4 w0[8], w1[8];
#pragma unroll
        for (int f = 0; f < 8; ++f) { w0[f] = wr0[f * 64 + lane]; w1[f] = wr1[f * 64 + lane]; }

        const float4* xr = (const float4*)(x + (size_t)b * N0_);
        float a0 = 0.f, a1 = 0.f;
#pragma unroll
        for (int f = 0; f < 8; ++f) {
            const float4 xv = xr[f * 64 + lane];
            a0 += w0[f].x * xv.x + w0[f].y * xv.y + w0[f].z * xv.z + w0[f].w * xv.w;
            a1 += w1[f].x * xv.x + w1[f].y * xv.y + w1[f].z * xv.z + w1[f].w * xv.w;
        }
        const float s0 = wred(a0), s1 = wred(a1);
        const float r0 = fmaxf(s0 + b1r[e * N3_ + j0],     0.f);
        const float r1 = fmaxf(s1 + b1r[e * N3_ + j0 + 1], 0.f);

        if (lane < 3) {
            const float* w2 = W2r + ((size_t)e * 3 + lane) * N3_;
            __hip_atomic_fetch_add(&y2acc[b * 3 + lane], r0 * w2[j0] + r1 * w2[j0 + 1],
                                   __ATOMIC_RELAXED, AGENT);
        }
        int old = 0;
        if (lane == 0) old = __hip_atomic_fetch_add(&cntr[b], 1, __ATOMIC_ACQ_REL, AGENT);
        old = __shfl(old, 0, 64);
        if (old == N3_ / 2 - 1 && lane < 3) {                 // last r task for this b
            const float vv = __hip_atomic_load(&y2acc[b * 3 + lane], __ATOMIC_RELAXED, AGENT);
            out_y2[b * 3 + lane] = vv + b2r[e * 3 + lane];
        }
    }
}

extern "C" void kernel_launch(void* const* d_in, const int* in_sizes, int n_in,
                              void* d_out, int out_size, void* d_ws, size_t ws_size,
                              hipStream_t stream) {
    const float* x   = (const float*)d_in[0];
    const int*   cls = (const int*)  d_in[1];
    const float* W1b = (const float*)d_in[2];
    const float* b1b = (const float*)d_in[3];
    const float* W2b = (const float*)d_in[4];
    const float* b2b = (const float*)d_in[5];
    const float* W3b = (const float*)d_in[6];
    const float* b3b = (const float*)d_in[7];
    const float* W1r = (const float*)d_in[8];
    const float* b1r = (const float*)d_in[9];
    const float* W2r = (const float*)d_in[10];
    const float* b2r = (const float*)d_in[11];

    float* out_y1 = (float*)d_out;                 // [0, 1024)
    float* out_y2 = (float*)d_out + B_ * NC_;      // [1024, 1216)

    char*  ws    = (char*)d_ws;
    float* h1    = (float*)(ws);                   // 256000 B
    // ---- zeroed region (5664 B, cleared by K1 block (0,0)) ----
    float* y1acc = (float*)(ws + 256000);          // 4096 B  (64*16)
    int*   cntb  = (int*)  (ws + 260096);          // 256 B
    int*   flag  = (int*)  (ws + 260352);          // 256 B
    int*   cntr  = (int*)  (ws + 260608);          // 256 B
    float* y2acc = (float*)(ws + 260864);          // 768 B
    int*   ctrs  = (int*)  (ws + 261632);          // 32 B
    int*   zbase = (int*)  (ws + 256000);

    hipLaunchKernelGGL(k_l1b, dim3(125, 12), dim3(256), 0, stream,
                       x, cls, W1b, b1b, h1, zbase);
    hipLaunchKernelGGL(k_fused2, dim3(768), dim3(256), 0, stream,
                       x, cls, h1, W2b, b2b, W3b, b3b, W1r, b1r, W2r, b2r,
                       y1acc, cntb, flag, cntr, y2acc, ctrs, out_y1, out_y2);
}

// Round 5
// 66.575 us; speedup vs baseline: 7.1273x; 7.1273x over previous
//
#include <hip/hip_runtime.h>

#define B_   64
#define C_   12
#define NC_  16
#define N0_  2048
#define N1_  1000
#define N2_  500
#define N3_  100

__device__ __forceinline__ float wred(float v) {
#pragma unroll
    for (int off = 32; off > 0; off >>= 1) v += __shfl_xor(v, off, 64);
    return v;
}

// ===== K1: h1 = relu(x·W1b^T + b1b). grid (125,12)×256, 2 rows/wave, no LDS. =====
__global__ __launch_bounds__(256)
void k_l1b(const float* __restrict__ x, const int* __restrict__ cls,
           const float* __restrict__ W1b, const float* __restrict__ b1b,
           float* __restrict__ h1) {
    const int c    = blockIdx.y;
    const int lane = threadIdx.x & 63;
    const int wave = threadIdx.x >> 6;
    const unsigned long long m = __ballot(cls[lane] == c);
    if (m == 0ull) return;

    const int j0 = blockIdx.x * 8 + wave * 2;                 // < 1000 always
    const float4* wr0 = (const float4*)(W1b + ((size_t)c * N1_ + j0) * N0_);
    const float4* wr1 = wr0 + (N0_ / 4);
    float4 w0[8], w1[8];
#pragma unroll
    for (int f = 0; f < 8; ++f) { w0[f] = wr0[f * 64 + lane]; w1[f] = wr1[f * 64 + lane]; }
    const float bias0 = b1b[c * N1_ + j0];
    const float bias1 = b1b[c * N1_ + j0 + 1];

    for (unsigned long long mm = m; mm; mm &= (mm - 1ull)) {
        const int b = (int)__builtin_ctzll(mm);
        const float4* xr = (const float4*)(x + (size_t)b * N0_);
        float a0 = 0.f, a1 = 0.f;
#pragma unroll
        for (int f = 0; f < 8; ++f) {
            const float4 xv = xr[f * 64 + lane];
            a0 += w0[f].x * xv.x + w0[f].y * xv.y + w0[f].z * xv.z + w0[f].w * xv.w;
            a1 += w1[f].x * xv.x + w1[f].y * xv.y + w1[f].z * xv.z + w1[f].w * xv.w;
        }
        const float s0 = wred(a0), s1 = wred(a1);
        if (lane == 0) {
            h1[(size_t)b * N1_ + j0]     = fmaxf(s0 + bias0, 0.f);
            h1[(size_t)b * N1_ + j0 + 1] = fmaxf(s1 + bias1, 0.f);
        }
    }
}

// ===== K2: one block per b — h2 -> y1 -> argmax -> r -> y2, all in-block. =====
// grid 64 × 1024 (16 waves). No atomics, no global intermediates.
__global__ __launch_bounds__(1024)
void k_perb(const float* __restrict__ x, const int* __restrict__ cls,
            const float* __restrict__ h1,
            const float* __restrict__ W2b, const float* __restrict__ b2b,
            const float* __restrict__ W3b, const float* __restrict__ b3b,
            const float* __restrict__ W1r, const float* __restrict__ b1r,
            const float* __restrict__ W2r, const float* __restrict__ b2r,
            float* __restrict__ out_y1, float* __restrict__ out_y2) {
    const int b    = blockIdx.x;
    const int tid  = threadIdx.x;
    const int lane = tid & 63;
    const int wave = tid >> 6;                     // 0..15
    const int c    = cls[b];

    __shared__ float s_x[N0_];                     // 8 KB
    __shared__ float s_h1[N1_];                    // 4 KB
    __shared__ float s_h2[N2_];                    // 2 KB
    __shared__ float s_y1[NC_];
    __shared__ float s_r[N3_];
    __shared__ int   s_e;

    for (int i = tid; i < N0_; i += 1024) s_x[i]  = x[(size_t)b * N0_ + i];
    for (int i = tid; i < N1_; i += 1024) s_h1[i] = h1[(size_t)b * N1_ + i];
    __syncthreads();

    // ---- h2[b][j] = relu(h1·W2b[c][j] + b2b), 500 rows, 2/wave/iter ----
    {
        const float4 z4 = make_float4(0.f, 0.f, 0.f, 0.f);
        const float4* xr = (const float4*)s_h1;    // 250 float4
        for (int j0 = wave * 2; j0 < N2_; j0 += 32) {
            const float4* wr0 = (const float4*)(W2b + ((size_t)c * N2_ + j0) * N1_);
            const float4* wr1 = wr0 + (N1_ / 4);
            float a0 = 0.f, a1 = 0.f;
#pragma unroll
            for (int f = 0; f < 4; ++f) {
                const int idx = f * 64 + lane;
                if (idx < N1_ / 4) {
                    const float4 xv = xr[idx];
                    const float4 w0 = wr0[idx], w1 = wr1[idx];
                    a0 += w0.x * xv.x + w0.y * xv.y + w0.z * xv.z + w0.w * xv.w;
                    a1 += w1.x * xv.x + w1.y * xv.y + w1.z * xv.z + w1.w * xv.w;
                }
            }
            const float s0 = wred(a0), s1 = wred(a1);
            if (lane == 0) {
                s_h2[j0]     = fmaxf(s0 + b2b[c * N2_ + j0],     0.f);
                s_h2[j0 + 1] = fmaxf(s1 + b2b[c * N2_ + j0 + 1], 0.f);
            }
        }
    }
    __syncthreads();

    // ---- y1[b][m] = h2·W3b[c][m] + b3b, wave m handles m ----
    if (wave < NC_) {
        const float* wrow = W3b + ((size_t)c * NC_ + wave) * N2_;
        float a = 0.f;
        for (int k = lane; k < N2_; k += 64) a += s_h2[k] * wrow[k];
        const float s = wred(a) + b3b[c * NC_ + wave];
        if (lane == 0) { s_y1[wave] = s; out_y1[b * NC_ + wave] = s; }
    }
    __syncthreads();

    // ---- argmax (first occurrence) by wave 0, lanes 0..15 ----
    if (wave == 0) {
        float v  = (lane < NC_) ? s_y1[lane] : -1e30f;
        int   mi = lane;
#pragma unroll
        for (int off = 8; off > 0; off >>= 1) {
            const float ov = __shfl_xor(v,  off, 16);
            const int   om = __shfl_xor(mi, off, 16);
            if (ov > v || (ov == v && om < mi)) { v = ov; mi = om; }
        }
        if (lane == 0) s_e = c * NC_ + mi;
    }
    __syncthreads();
    const int e = s_e;

    // ---- r[b][j] = relu(x·W1r[e][j] + b1r), 100 rows, 2/wave/iter ----
    {
        const float4* xr = (const float4*)s_x;     // 512 float4
        for (int j0 = wave * 2; j0 < N3_; j0 += 32) {
            const float4* wr0 = (const float4*)(W1r + ((size_t)e * N3_ + j0) * N0_);
            const float4* wr1 = wr0 + (N0_ / 4);
            float a0 = 0.f, a1 = 0.f;
#pragma unroll
            for (int f = 0; f < 8; ++f) {
                const int idx = f * 64 + lane;
                const float4 xv = xr[idx];
                const float4 w0 = wr0[idx], w1 = wr1[idx];
                a0 += w0.x * xv.x + w0.y * xv.y + w0.z * xv.z + w0.w * xv.w;
                a1 += w1.x * xv.x + w1.y * xv.y + w1.z * xv.z + w1.w * xv.w;
            }
            const float s0 = wred(a0), s1 = wred(a1);
            if (lane == 0) {
                s_r[j0]     = fmaxf(s0 + b1r[e * N3_ + j0],     0.f);
                s_r[j0 + 1] = fmaxf(s1 + b1r[e * N3_ + j0 + 1], 0.f);
            }
        }
    }
    __syncthreads();

    // ---- y2[b][d] = r·W2r[e][d] + b2r, wave d handles d ----
    if (wave < 3) {
        const float* w2 = W2r + ((size_t)e * 3 + wave) * N3_;
        float a = s_r[lane] * w2[lane];
        if (lane < N3_ - 64) a += s_r[64 + lane] * w2[64 + lane];
        const float s = wred(a);
        if (lane == 0) out_y2[b * 3 + wave] = s + b2r[e * 3 + wave];
    }
}

extern "C" void kernel_launch(void* const* d_in, const int* in_sizes, int n_in,
                              void* d_out, int out_size, void* d_ws, size_t ws_size,
                              hipStream_t stream) {
    const float* x   = (const float*)d_in[0];
    const int*   cls = (const int*)  d_in[1];
    const float* W1b = (const float*)d_in[2];
    const float* b1b = (const float*)d_in[3];
    const float* W2b = (const float*)d_in[4];
    const float* b2b = (const float*)d_in[5];
    const float* W3b = (const float*)d_in[6];
    const float* b3b = (const float*)d_in[7];
    const float* W1r = (const float*)d_in[8];
    const float* b1r = (const float*)d_in[9];
    const float* W2r = (const float*)d_in[10];
    const float* b2r = (const float*)d_in[11];

    float* out_y1 = (float*)d_out;                 // [0, 1024)
    float* out_y2 = (float*)d_out + B_ * NC_;      // [1024, 1216)
    float* h1     = (float*)d_ws;                  // 256000 B

    hipLaunchKernelGGL(k_l1b, dim3(125, 12), dim3(256), 0, stream,
                       x, cls, W1b, b1b, h1);
    hipLaunchKernelGGL(k_perb, dim3(64), dim3(1024), 0, stream,
                       x, cls, h1, W2b, b2b, W3b, b3b, W1r, b1r, W2r, b2r,
                       out_y1, out_y2);
}